// Round 5
// baseline (118.380 us; speedup 1.0000x reference)
//
#include <hip/hip_runtime.h>
#include <math.h>

typedef float f32x4 __attribute__((ext_vector_type(4)));

#define NF 69u                        // floats per output row (1 + 68)
#define WROWS 64u                     // rows per wave-tile (lane = row)
#define WTILE_FLOATS (WROWS * NF)     // 4416 floats = 17664 B per wave
#define WTILE_F4 (WTILE_FLOATS / 4u)  // 1104 float4s
#define NCHUNK 18u                    // ceil(1104 / 64): 17 full + 1 masked
#define BLOCK 256u
#define WAVES 4u

// ---------------------------------------------------------------------------
// Kernel 1: per-axis feature tables, PADDED to stride 8 for aligned f32x4
// loads. tab8[c*8 + ft] for x-axis, tab8[8*W + c*8 + ft] for y-axis,
// ft in [0,5): norm,sign,sin,cos,rtan. Pads [5..8) unwritten/unread.
// ---------------------------------------------------------------------------
__global__ void pe_table_kernel(const int* __restrict__ hptr,
                                const int* __restrict__ wptr,
                                float* __restrict__ tab8) {
    const int H = *hptr;
    const int W = *wptr;
    const int total = W + H;
    for (int i = (int)(blockIdx.x * blockDim.x + threadIdx.x); i < total;
         i += (int)(gridDim.x * blockDim.x)) {
        const bool is_y = (i >= W);
        const int c = is_y ? (i - W) : i;
        const int size = is_y ? H : W;
        double norm = 0.0, angle = 0.0;
        if (size > 1) {
            const double r = (double)c / (double)(size - 1);
            norm = 2.0 * r - 1.0;
            angle = M_PI * r;
        }
        const double d = (double)c - 0.5 * (double)size;
        const float sgn = (d > 0.0) ? 1.0f : ((d < 0.0) ? -1.0f : 0.0f);
        const int base = (is_y ? 8 * W : 0) + 8 * c;
        tab8[base + 0] = (float)norm;
        tab8[base + 1] = sgn;
        tab8[base + 2] = (float)sin(angle);
        tab8[base + 3] = (float)cos(angle);
        tab8[base + 4] = (float)rint(tan(angle));
    }
}

// ---------------------------------------------------------------------------
// Kernel 2: wave-private 64-row tiles, zero barriers, persistent-zero one-hot
// region, and a compile-time-unrolled 18-deep LDS->global store batch.
// ---------------------------------------------------------------------------
__global__ __launch_bounds__(BLOCK) void pe_main_kernel(
    const float* __restrict__ x,
    const int* __restrict__ hptr, const int* __restrict__ wptr,
    const float* __restrict__ tab8,
    float* __restrict__ out, unsigned int Q /* = B*H*W rows */) {
    __shared__ __align__(16) float lds[WAVES][WTILE_FLOATS];  // 70656 B

    const unsigned int W = (unsigned int)*wptr;
    const unsigned int H = (unsigned int)*hptr;
    const unsigned int yoff8 = 8u * W;
    const unsigned int lane = threadIdx.x & 63u;
    const unsigned int wid = threadIdx.x >> 6;
    float* buf = lds[wid];

    // One-time zero of this wave's private buffer (wave-local, no barrier).
    {
        f32x4 z = {0.f, 0.f, 0.f, 0.f};
        f32x4* bp = (f32x4*)buf;
        for (unsigned int j = lane; j < WTILE_F4; j += 64u) bp[j] = z;
    }

    const unsigned int ntiles = (Q + WROWS - 1u) / WROWS;
    const unsigned int gw = blockIdx.x * WAVES + wid;   // global wave id
    const unsigned int nw = gridDim.x * WAVES;

    for (unsigned int T = gw; T < ntiles; T += nw) {
        const unsigned int q = T * WROWS + lane;
        unsigned int w = 0u, h = 0u;
        const bool valid = q < Q;
        if (valid) {
            const unsigned int t = q / W;   // q = (b*H + h)*W + w
            w = q - t * W;
            h = t - (t / H) * H;
            float* row = buf + lane * NF;
            row[0] = x[q];
            // aligned f32x4 + scalar table loads (stride-8 layout)
            const f32x4 xa = *(const f32x4*)(tab8 + 8u * w);
            const float xa4 = tab8[8u * w + 4u];
            const f32x4 ya = *(const f32x4*)(tab8 + yoff8 + 8u * h);
            const float ya4 = tab8[yoff8 + 8u * h + 4u];
            row[1] = xa[0]; row[2]  = ya[0];
            row[3] = xa[1]; row[4]  = ya[1];
            row[5] = xa[2]; row[6]  = ya[2];
            row[7] = xa[3]; row[8]  = ya[3];
            row[9] = xa4;   row[10] = ya4;
            if (w < 29u) row[11u + w] = 1.0f;   // one-hot x poke
            if (h < 29u) row[40u + h] = 1.0f;   // one-hot y poke
        }

        const unsigned int rem = Q - T * WROWS;
        const size_t obase = (size_t)T * (size_t)WTILE_FLOATS;
        const f32x4* lp = (const f32x4*)buf;
        f32x4* op = (f32x4*)(out + obase);      // 4416*T floats: 16B-aligned

        if (rem >= WROWS) {
            // ---- full tile: batched 18-deep unrolled copy ----
            f32x4 v[NCHUNK];
#pragma unroll
            for (unsigned int j = 0u; j < NCHUNK; ++j) {
                const unsigned int idx = lane + 64u * j;
                if (j < NCHUNK - 1u || idx < WTILE_F4) v[j] = lp[idx];
            }
#pragma unroll
            for (unsigned int j = 0u; j < NCHUNK; ++j) {
                const unsigned int idx = lane + 64u * j;
                if (j < NCHUNK - 1u || idx < WTILE_F4)
                    __builtin_nontemporal_store(v[j], op + idx);
            }
        } else {
            // ---- partial tail tile (not hit for the bench shape) ----
            const unsigned int nfl = rem * NF;
            const unsigned int n4 = nfl >> 2;
            for (unsigned int j = lane; j < n4; j += 64u)
                __builtin_nontemporal_store(lp[j], op + j);
            for (unsigned int j = (n4 << 2) + lane; j < nfl; j += 64u)
                __builtin_nontemporal_store(buf[j], out + obase + j);
        }

        // ---- restore poked one-hot slots to zero ----
        if (valid) {
            float* row = buf + lane * NF;
            if (w < 29u) row[11u + w] = 0.0f;
            if (h < 29u) row[40u + h] = 0.0f;
        }
    }
}

extern "C" void kernel_launch(void* const* d_in, const int* in_sizes, int n_in,
                              void* d_out, int out_size, void* d_ws, size_t ws_size,
                              hipStream_t stream) {
    const float* x = (const float*)d_in[0];
    const int* hptr = (const int*)d_in[1];
    const int* wptr = (const int*)d_in[2];
    float* out = (float*)d_out;
    float* tab8 = (float*)d_ws;  // (W+H)*8*4 B = 32 KB for the bench shape

    pe_table_kernel<<<8, 256, 0, stream>>>(hptr, wptr, tab8);

    const unsigned int Q = (unsigned int)in_sizes[0];  // B*H*W rows
    const unsigned int ntiles = (Q + WROWS - 1u) / WROWS;
    unsigned int blocks = (ntiles + WAVES - 1u) / WAVES;
    if (blocks > 2048u) blocks = 2048u;
    if (blocks == 0u) blocks = 1u;
    pe_main_kernel<<<blocks, BLOCK, 0, stream>>>(x, hptr, wptr, tab8, out, Q);
}